// Round 6
// baseline (130.966 us; speedup 1.0000x reference)
//
#include <hip/hip_runtime.h>
#include <hip/hip_bf16.h>
#include <stdint.h>

#define T_DIM 1024
#define B_DIM 8

typedef __attribute__((ext_vector_type(8))) short short8;
typedef __attribute__((ext_vector_type(4))) float f32x4;

__device__ inline void gll16(const void* g, void* l) {
  __builtin_amdgcn_global_load_lds((__attribute__((address_space(1))) void*)g,
                                   (__attribute__((address_space(3))) void*)l,
                                   16, 0, 0);
}

// ---------------- fp32 -> bf16 convert ----------------
__global__ __launch_bounds__(256) void convert_kernel(const float* __restrict__ F,
                                                      __hip_bfloat16* __restrict__ Fb) {
  const int t = blockIdx.x * 256 + threadIdx.x;
  const float4 v = ((const float4*)F)[t];
  union { __hip_bfloat16 h[4]; uint64_t u; } p;
  p.h[0] = __float2bfloat16(v.x);
  p.h[1] = __float2bfloat16(v.y);
  p.h[2] = __float2bfloat16(v.z);
  p.h[3] = __float2bfloat16(v.w);
  ((uint64_t*)Fb)[t] = p.u;
}

// ---------------- fused Gram + row-partial kernel (triangular strips) ----------------
// Round-6: 128x64 strip-cells (ct2 = 64-col strip, valid when ct2 >= 2*rt):
// 72 blocks/batch = 576 total = 2.25 blocks/CU resident (round-5's 36/XCD =
// 1.125/CU starved latency hiding -> fused got SLOWER despite half the MACs).
// 256 threads / 4 waves, each wave owns 32 rows x 64 cols. LDS 48 KB
// (A 2x16KB + B 2x8KB) -> 3 blocks/CU capacity. Forward epilogue: every row
// owned by one wave -> direct part writes, no LDS merge. Mirror (skipped for
// ct2 in {2rt,2rt+1}: diag 128x128 block fully covered by forward) reduces
// over cols' = rt-tile (all < L since ct2>=2rt+2), wave-pairs {0,1}/{2,3}
// -> slots 2rt / 2rt+1. part has 16 slots/row (64-col strips).
__global__ __launch_bounds__(256, 4) void fused_kernel(const __hip_bfloat16* __restrict__ Fb,
                                                       const float* __restrict__ M,
                                                       const int* __restrict__ icl,
                                                       float* __restrict__ part) {
  const int id = blockIdx.x;
  const int b  = id & 7;          // XCD = wgid % 8 -> all tiles of batch b on one XCD
  int k = id >> 3;                // 0..71 triangular strip index
  int rt = 0;
  while (k >= 16 - 2 * rt) { k -= 16 - 2 * rt; rt++; }
  const int ct2 = 2 * rt + k;     // 64-col strip, ct2 >= 2*rt
  const int L  = icl[b] + 1;
  if (ct2 * 64 >= L) return;      // strip fully invalid (rows handled by reduce)

  __shared__ char smem[49152];
  __hip_bfloat16* As = (__hip_bfloat16*)smem;            // [2buf][2kk][128][32] = 32 KB
  __hip_bfloat16* Bs = (__hip_bfloat16*)(smem + 32768);  // [2buf][2kk][64][32] = 16 KB
  float* rp2 = (float*)smem;      // mirror merge after K-loop: 5 x [64][4]
  float* rp2_m = rp2;
  float* rp2_d = rp2 + 256;
  float* rp2_s = rp2 + 512;
  float* rp2_c = rp2 + 768;
  float* rp2_b = rp2 + 1024;

  const __hip_bfloat16* F = Fb + ((size_t)b << 20);
  const int tid  = threadIdx.x;
  const int lane = tid & 63;
  const int wave = tid >> 6;            // 0..3
  const int wrow = wave * 32;           // wave's 32-row patch
  const int row0 = rt * 128;
  const int col0 = ct2 * 64;
  const bool mirror = (ct2 >= 2 * rt + 2);

  const int fr = lane & 15;             // fragment index within 16
  const int q  = lane >> 4;             // quarter-wave (k-granule)
  const int sl8 = (q ^ ((fr >> 1) & 3)) * 8;   // swizzled slot (elements)

  // staging: thread t -> row t>>2, granule t&3; source granule = swizzle^-1
  const int srow = tid >> 2;                                  // 0..63
  const int sgk  = (((tid & 3) ^ ((tid >> 3) & 3)) * 8);      // source k offset

  auto stage = [&](int buf, int step) {
    const int kb = step << 6;     // BK = 64
#pragma unroll
    for (int kk = 0; kk < 2; kk++) {
#pragma unroll
      for (int h = 0; h < 2; h++)   // A: 128 rows in two 64-row sweeps
        gll16(F + (size_t)(row0 + h * 64 + srow) * T_DIM + kb + kk * 32 + sgk,
              As + buf * 8192 + kk * 4096 + h * 2048 + tid * 8);
      gll16(F + (size_t)(col0 + srow) * T_DIM + kb + kk * 32 + sgk,
            Bs + buf * 4096 + kk * 2048 + tid * 8);
    }
  };

  // prologue: two tiles in flight (12 gll16)
  stage(0, 0);
  stage(1, 1);

  f32x4 acc[2][4];
#pragma unroll
  for (int i = 0; i < 2; i++)
#pragma unroll
    for (int j = 0; j < 4; j++) acc[i][j] = (f32x4){0.f, 0.f, 0.f, 0.f};

#pragma unroll
  for (int t = 0; t < 16; ++t) {
    const int cur = t & 1;
    // own tile-t loads landed; tile-(t+1) loads (6) stay in flight
    if (t < 15) { asm volatile("s_waitcnt vmcnt(6)" ::: "memory"); }
    else        { asm volatile("s_waitcnt vmcnt(0)" ::: "memory"); }
    __builtin_amdgcn_s_barrier();                 // (A) tile t visible
    __builtin_amdgcn_sched_barrier(0);

    short8 af[2][2], bfr[2][4];
    const __hip_bfloat16* Ab = As + cur * 8192;
    const __hip_bfloat16* Bb = Bs + cur * 4096;
#pragma unroll
    for (int kk = 0; kk < 2; kk++) {
#pragma unroll
      for (int ti = 0; ti < 2; ti++)
        af[kk][ti] = *(const short8*)(Ab + kk * 4096 + (wrow + ti * 16 + fr) * 32 + sl8);
#pragma unroll
      for (int tj = 0; tj < 4; tj++)
        bfr[kk][tj] = *(const short8*)(Bb + kk * 2048 + (tj * 16 + fr) * 32 + sl8);
    }
    asm volatile("s_waitcnt lgkmcnt(0)" ::: "memory");
    __builtin_amdgcn_sched_barrier(0);
    __builtin_amdgcn_s_barrier();                 // (B) all reads done -> buf free
    __builtin_amdgcn_sched_barrier(0);

    if (t < 14) stage(cur, t + 2);                // refill freed buffer

    // SWAPPED operands -> transposed C/D: lane fr = row, regs (q,r) = cols
    __builtin_amdgcn_s_setprio(1);
#pragma unroll
    for (int kk = 0; kk < 2; kk++)
#pragma unroll
      for (int ti = 0; ti < 2; ti++)
#pragma unroll
        for (int tj = 0; tj < 4; tj++)
          acc[ti][tj] = __builtin_amdgcn_mfma_f32_16x16x32_bf16(bfr[kk][tj], af[kk][ti], acc[ti][tj], 0, 0, 0);
    __builtin_amdgcn_s_setprio(0);
  }
  __syncthreads();   // all frag reads done before rp2 aliases staging LDS

  const float* Mb = M + ((size_t)b << 20);

  // ---- forward epilogue: row = row0+wrow+ti*16+fr, col = col0+tj*16+q*4+r ----
  uint32_t mbits = 0;   // bit = ti*16 + tj*4 + r
  {
    union { float4 v; float f[4]; } mv[2][4];
#pragma unroll
    for (int ti = 0; ti < 2; ti++) {
      const int grow = row0 + wrow + ti * 16 + fr;
#pragma unroll
      for (int tj = 0; tj < 4; tj++)
        mv[ti][tj].v = *(const float4*)(Mb + ((size_t)grow << 10) + col0 + tj * 16 + q * 4);
    }
#pragma unroll
    for (int ti = 0; ti < 2; ti++)
#pragma unroll
      for (int tj = 0; tj < 4; tj++)
#pragma unroll
        for (int r = 0; r < 4; r++)
          mbits |= ((mv[ti][tj].f[r] != 0.f) ? 1u : 0u) << (ti * 16 + tj * 4 + r);
  }

#pragma unroll
  for (int ti = 0; ti < 2; ti++) {
    const int grow = row0 + wrow + ti * 16 + fr;
    float s[4][4];
#pragma unroll
    for (int tj = 0; tj < 4; tj++)
#pragma unroll
      for (int r = 0; r < 4; r++) {
        const int gcol = col0 + tj * 16 + q * 4 + r;
        s[tj][r] = (gcol < L) ? acc[ti][tj][r] * 10.0f : -1e30f;
      }
    float m = s[0][0];
#pragma unroll
    for (int tj = 0; tj < 4; tj++)
#pragma unroll
      for (int r = 0; r < 4; r++) m = fmaxf(m, s[tj][r]);
    m = fmaxf(m, __shfl_xor(m, 16, 64));
    m = fmaxf(m, __shfl_xor(m, 32, 64));

    float den = 0.f, msum = 0.f, cnt = 0.f, badf = 0.f;
#pragma unroll
    for (int tj = 0; tj < 4; tj++)
#pragma unroll
      for (int r = 0; r < 4; r++) {
        const int gcol = col0 + tj * 16 + q * 4 + r;
        if (gcol < L) {
          const float mk = (float)((mbits >> (ti * 16 + tj * 4 + r)) & 1u);
          if (gcol != grow) {
            den  += __expf(s[tj][r] - m);
            msum += mk * s[tj][r];
            cnt  += mk;
          }
          const float sane = (gcol == grow && grow != 0) ? 1.f : 0.f;
          badf = fmaxf(badf, (mk != sane) ? 1.f : 0.f);
        }
      }
    den  += __shfl_xor(den, 16, 64);  den  += __shfl_xor(den, 32, 64);
    msum += __shfl_xor(msum, 16, 64); msum += __shfl_xor(msum, 32, 64);
    cnt  += __shfl_xor(cnt, 16, 64);  cnt  += __shfl_xor(cnt, 32, 64);
    badf = fmaxf(badf, __shfl_xor(badf, 16, 64));
    badf = fmaxf(badf, __shfl_xor(badf, 32, 64));

    if (lane < 16) {  // q == 0: this lane owns row grow exclusively
      float* p = part + ((((size_t)b * 1024 + grow) * 16) + ct2) * 5;
      p[0] = m; p[1] = den; p[2] = msum; p[3] = cnt; p[4] = badf;
    }
  }

  // ---- mirror epilogue: rows' = strip ct2, cols' = rt-tile (all < L) ----
  if (mirror) {
    uint32_t mtbits = 0;    // bit = (tj*4+r)*2 + ti
#pragma unroll
    for (int tj = 0; tj < 4; tj++)
#pragma unroll
      for (int r = 0; r < 4; r++) {
        const int rowp = col0 + tj * 16 + q * 4 + r;
#pragma unroll
        for (int ti = 0; ti < 2; ti++) {
          const int colp = row0 + wrow + ti * 16 + fr;
          mtbits |= ((Mb[((size_t)rowp << 10) + colp] != 0.f) ? 1u : 0u)
                    << ((tj * 4 + r) * 2 + ti);
        }
      }
#pragma unroll
    for (int tj = 0; tj < 4; tj++)
#pragma unroll
      for (int r = 0; r < 4; r++) {
        const float sv0 = acc[0][tj][r] * 10.0f;
        const float sv1 = acc[1][tj][r] * 10.0f;
        float mT = fmaxf(sv0, sv1);
#pragma unroll
        for (int d = 1; d < 16; d <<= 1) mT = fmaxf(mT, __shfl_xor(mT, d, 64));
        const float mk0 = (float)((mtbits >> ((tj * 4 + r) * 2)) & 1u);
        const float mk1 = (float)((mtbits >> ((tj * 4 + r) * 2 + 1)) & 1u);
        float denT  = __expf(sv0 - mT) + __expf(sv1 - mT);
        float msumT = mk0 * sv0 + mk1 * sv1;
        float cntT  = mk0 + mk1;
        float badT  = fmaxf(mk0, mk1);    // sane = 0: region strictly off-diag
#pragma unroll
        for (int d = 1; d < 16; d <<= 1) {
          denT  += __shfl_xor(denT, d, 64);
          msumT += __shfl_xor(msumT, d, 64);
          cntT  += __shfl_xor(cntT, d, 64);
          badT   = fmaxf(badT, __shfl_xor(badT, d, 64));
        }
        if (fr == 0) {
          const int lrowp = tj * 16 + q * 4 + r;   // 0..63 local row'
          rp2_m[lrowp * 4 + wave] = mT;    rp2_d[lrowp * 4 + wave] = denT;
          rp2_s[lrowp * 4 + wave] = msumT; rp2_c[lrowp * 4 + wave] = cntT;
          rp2_b[lrowp * 4 + wave] = badT;
        }
      }
  }
  __syncthreads();

  if (mirror && tid < 64) {
    // waves {0,1} cover cols' strip 2rt; waves {2,3} cover strip 2rt+1
#pragma unroll
    for (int pr = 0; pr < 2; pr++) {
      const float m0 = rp2_m[tid * 4 + pr * 2], m1 = rp2_m[tid * 4 + pr * 2 + 1];
      const float mT = fmaxf(m0, m1);
      const float denT = rp2_d[tid * 4 + pr * 2] * __expf(m0 - mT) +
                         rp2_d[tid * 4 + pr * 2 + 1] * __expf(m1 - mT);
      float* p2 = part + ((((size_t)b * 1024 + col0 + tid) * 16) + (2 * rt + pr)) * 5;
      p2[0] = mT;
      p2[1] = denT;
      p2[2] = rp2_s[tid * 4 + pr * 2] + rp2_s[tid * 4 + pr * 2 + 1];
      p2[3] = rp2_c[tid * 4 + pr * 2] + rp2_c[tid * 4 + pr * 2 + 1];
      p2[4] = fmaxf(rp2_b[tid * 4 + pr * 2], rp2_b[tid * 4 + pr * 2 + 1]);
    }
  }
}

// ---------------- reduce: merge 16 strip slots per row ----------------
__global__ __launch_bounds__(256) void reduce_kernel(const float* __restrict__ part,
                                                     const int* __restrict__ icl,
                                                     float* __restrict__ blk_sum,
                                                     int* __restrict__ blk_bad) {
  const int blk = blockIdx.x;
  const int row = blk * 256 + threadIdx.x;   // 0..8191
  const int b = row >> 10;
  const int i = row & 1023;
  const int L = icl[b] + 1;
  float rv = 0.f;
  int bad = 0;
  if (i < L) {
    const float* p = part + (size_t)row * 80;
    const int ns = (L + 63) >> 6;            // valid 64-col strips
    float m = -1e30f;
    for (int s = 0; s < ns; s++) m = fmaxf(m, p[s * 5 + 0]);
    float den = 0.f, msum = 0.f, cnt = 0.f, badf = 0.f;
    for (int s = 0; s < ns; s++) {
      den  += p[s * 5 + 1] * __expf(p[s * 5 + 0] - m);
      msum += p[s * 5 + 2];
      cnt  += p[s * 5 + 3];
      badf  = fmaxf(badf, p[s * 5 + 4]);
    }
    const float A = msum - cnt * m;          // sum mask*(s - mx)
    const float mlpp = (A - cnt * __logf(den + 1e-6f)) / (cnt + 1e-6f);
    rv = -mlpp / (float)L;
    bad = badf > 0.f ? 1 : 0;
  }
  const int tid  = threadIdx.x;
  const int lane = tid & 63;
  const int wave = tid >> 6;
  for (int o = 32; o > 0; o >>= 1) rv += __shfl_down(rv, o, 64);
  const int wbad = (__ballot(bad) != 0ull) ? 1 : 0;
  __shared__ float sred[4];
  __shared__ int bred[4];
  if (lane == 0) { sred[wave] = rv; bred[wave] = wbad; }
  __syncthreads();
  if (tid == 0) {
    blk_sum[blk] = sred[0] + sred[1] + sred[2] + sred[3];
    blk_bad[blk] = bred[0] | bred[1] | bred[2] | bred[3];
  }
}

// ---------------- finalize (single wave, deterministic) ----------------
__global__ __launch_bounds__(64) void final_kernel(const float* __restrict__ blk_sum,
                                                   const int* __restrict__ blk_bad,
                                                   float* __restrict__ out) {
  const int tid = threadIdx.x;
  float v = (tid < 32) ? blk_sum[tid] : 0.f;
  for (int o = 32; o > 0; o >>= 1) v += __shfl_down(v, o, 64);
  if (tid == 0) {
    int vcount = 0;
    for (int bb = 0; bb < B_DIM; bb++) {
      const int any = blk_bad[bb * 4] | blk_bad[bb * 4 + 1] |
                      blk_bad[bb * 4 + 2] | blk_bad[bb * 4 + 3];
      vcount += any ? 1 : 0;
    }
    out[0] = v / fmaxf((float)vcount, 1.0f);
  }
}

extern "C" void kernel_launch(void* const* d_in, const int* in_sizes, int n_in,
                              void* d_out, int out_size, void* d_ws, size_t ws_size,
                              hipStream_t stream) {
  const float* feat = (const float*)d_in[0];
  const float* mask = (const float*)d_in[1];
  const int*   icl  = (const int*)d_in[2];
  float* out = (float*)d_out;

  char* ws = (char*)d_ws;
  __hip_bfloat16* Fb = (__hip_bfloat16*)ws;                 // 16 MiB
  float* part    = (float*)(ws + (16u << 20));              // 2.62 MiB
  float* blk_sum = (float*)(ws + (19u << 20));              // 128 B
  int*   blk_bad = (int*)(ws + (19u << 20) + 512);          // 128 B

  convert_kernel<<<dim3(8192), dim3(256), 0, stream>>>(feat, Fb);
  fused_kernel<<<dim3(576), dim3(256), 0, stream>>>(Fb, mask, icl, part);
  reduce_kernel<<<dim3(32), dim3(256), 0, stream>>>(part, icl, blk_sum, blk_bad);
  final_kernel<<<dim3(1), dim3(64), 0, stream>>>(blk_sum, blk_bad, out);
}

// Round 7
// 126.825 us; speedup vs baseline: 1.0327x; 1.0327x over previous
//
#include <hip/hip_runtime.h>
#include <hip/hip_bf16.h>
#include <stdint.h>

#define T_DIM 1024
#define B_DIM 8

typedef __attribute__((ext_vector_type(8))) short short8;
typedef __attribute__((ext_vector_type(4))) float f32x4;

__device__ inline void gll16(const void* g, void* l) {
  __builtin_amdgcn_global_load_lds((__attribute__((address_space(1))) void*)g,
                                   (__attribute__((address_space(3))) void*)l,
                                   16, 0, 0);
}

// ---------------- fp32 -> bf16 convert ----------------
__global__ __launch_bounds__(256) void convert_kernel(const float* __restrict__ F,
                                                      __hip_bfloat16* __restrict__ Fb) {
  const int t = blockIdx.x * 256 + threadIdx.x;
  const float4 v = ((const float4*)F)[t];
  union { __hip_bfloat16 h[4]; uint64_t u; } p;
  p.h[0] = __float2bfloat16(v.x);
  p.h[1] = __float2bfloat16(v.y);
  p.h[2] = __float2bfloat16(v.z);
  p.h[3] = __float2bfloat16(v.w);
  ((uint64_t*)Fb)[t] = p.u;
}

// ---------------- fused Gram + row-partial kernel ----------------
// Round-7: exact revert to the round-3 structure (measured best: 120.35 us,
// fused ~27 us). Cross-round evidence: full grid @ 512 thr / 2 blocks/CU =
// 16 waves/CU beats every lower-occupancy variant regardless of MAC count
// (R5 tri 9 waves: +5.6us; R6 strips 9 waves: +11us; R4 reg-staging: +20us).
// ONE new delta vs R3: the 8 mask float4 loads are hoisted to the prologue
// (issued before the stage calls, packed immediately to the 1-reg mbits) so
// their cold-HBM latency hides under prologue staging instead of serializing
// at the block tail. Pack waits vmcnt(8) -> both stage groups stay in
// flight; t=0's vmcnt(4) arithmetic unchanged.
__global__ __launch_bounds__(512, 4) void fused_kernel(const __hip_bfloat16* __restrict__ Fb,
                                                       const float* __restrict__ M,
                                                       const int* __restrict__ icl,
                                                       float* __restrict__ part) {
  const int id = blockIdx.x;
  const int b  = id & 7;          // XCD = wgid % 8 -> all tiles of batch b on one XCD
  const int rt = (id >> 3) & 7;
  const int ct = id >> 6;
  const int L  = icl[b] + 1;
  if (rt * 128 >= L || ct * 128 >= L) return;   // tile fully invalid (uniform exit)

  __shared__ char smem[65536];
  __hip_bfloat16* As = (__hip_bfloat16*)smem;            // [2 buf][2 kk][128][32] = 32 KB
  __hip_bfloat16* Bs = (__hip_bfloat16*)(smem + 32768);  // 32 KB
  float* rp = (float*)smem;  // reused after K-loop: 5 arrays of 128x4 floats
  float* rp_m = rp;          // [row*4 + slot]
  float* rp_d = rp + 512;
  float* rp_s = rp + 1024;
  float* rp_c = rp + 1536;
  float* rp_b = rp + 2048;

  const __hip_bfloat16* F = Fb + ((size_t)b << 20);
  const int tid  = threadIdx.x;
  const int lane = tid & 63;
  const int wave = tid >> 6;            // 0..7
  const int wrow = (wave >> 2) * 64;    // 0 / 64
  const int wcol = (wave & 3) * 32;     // 0 / 32 / 64 / 96
  const int row0 = rt * 128;
  const int col0 = ct * 128;

  const int fr = lane & 15;             // fragment index within 16
  const int q  = lane >> 4;             // quarter-wave (k-granule)
  const int sl8 = (q ^ ((fr >> 1) & 3)) * 8;   // swizzled slot (elements)

  // staging: thread l -> LDS row l>>2, slot l&3; source granule = swizzle^-1
  const int srow = tid >> 2;                                  // 0..127
  const int sgk  = (((tid & 3) ^ ((tid >> 3) & 3)) * 8);      // source k offset

  const size_t arow = (size_t)(row0 + srow) * T_DIM + sgk;
  const size_t brow = (size_t)(col0 + srow) * T_DIM + sgk;

  auto stage = [&](int buf, int step) {
    const int kb = step << 6;     // BK = 64
#pragma unroll
    for (int p = 0; p < 2; p++)
      gll16(F + arow + kb + p * 32, As + buf * 8192 + p * 4096 + tid * 8);
#pragma unroll
    for (int p = 0; p < 2; p++)
      gll16(F + brow + kb + p * 32, Bs + buf * 8192 + p * 4096 + tid * 8);
  };

  // ---- mask loads: issue BEFORE staging so latency hides under prologue ----
  union { float4 v; float f[4]; } mv[4][2];
  {
    const float* Mb = M + ((size_t)b << 20);
#pragma unroll
    for (int ti = 0; ti < 4; ti++) {
      const int grow = row0 + wrow + ti * 16 + fr;
#pragma unroll
      for (int tj = 0; tj < 2; tj++)
        mv[ti][tj].v = *(const float4*)(Mb + ((size_t)grow << 10) + col0 + wcol + tj * 16 + q * 4);
    }
  }

  // prologue: two tiles in flight (8 gll16)
  stage(0, 0);
  stage(1, 1);

  // pack mask bits (compiler waits mask loads with vmcnt(8): stages keep flying)
  uint32_t mbits = 0;   // bit = ti*8 + tj*4 + r
#pragma unroll
  for (int ti = 0; ti < 4; ti++)
#pragma unroll
    for (int tj = 0; tj < 2; tj++)
#pragma unroll
      for (int r = 0; r < 4; r++)
        mbits |= ((mv[ti][tj].f[r] != 0.f) ? 1u : 0u) << (ti * 8 + tj * 4 + r);

  f32x4 acc[4][2];
#pragma unroll
  for (int i = 0; i < 4; i++)
#pragma unroll
    for (int j = 0; j < 2; j++) acc[i][j] = (f32x4){0.f, 0.f, 0.f, 0.f};

#pragma unroll
  for (int t = 0; t < 16; ++t) {
    const int cur = t & 1;
    // own tile-t loads landed; tile-(t+1) loads (4) stay in flight
    if (t < 15) { asm volatile("s_waitcnt vmcnt(4)" ::: "memory"); }
    else        { asm volatile("s_waitcnt vmcnt(0)" ::: "memory"); }
    __builtin_amdgcn_s_barrier();                 // (A) tile t visible everywhere
    __builtin_amdgcn_sched_barrier(0);

    short8 af[2][4], bfr[2][2];
    const __hip_bfloat16* Ab = As + cur * 8192;
    const __hip_bfloat16* Bb = Bs + cur * 8192;
#pragma unroll
    for (int kk = 0; kk < 2; kk++) {
#pragma unroll
      for (int tt = 0; tt < 4; tt++)
        af[kk][tt] = *(const short8*)(Ab + kk * 4096 + (wrow + tt * 16 + fr) * 32 + sl8);
#pragma unroll
      for (int j = 0; j < 2; j++)
        bfr[kk][j] = *(const short8*)(Bb + kk * 4096 + (wcol + j * 16 + fr) * 32 + sl8);
    }
    asm volatile("s_waitcnt lgkmcnt(0)" ::: "memory");
    __builtin_amdgcn_sched_barrier(0);
    __builtin_amdgcn_s_barrier();                 // (B) all reads done -> buf free
    __builtin_amdgcn_sched_barrier(0);

    if (t < 14) stage(cur, t + 2);                // refill freed buffer

    // SWAPPED operand order -> transposed C/D: lane fr = row, regs (q,r) = cols
    __builtin_amdgcn_s_setprio(1);
#pragma unroll
    for (int kk = 0; kk < 2; kk++)
#pragma unroll
      for (int ti = 0; ti < 4; ti++)
#pragma unroll
        for (int tj = 0; tj < 2; tj++)
          acc[ti][tj] = __builtin_amdgcn_mfma_f32_16x16x32_bf16(bfr[kk][tj], af[kk][ti], acc[ti][tj], 0, 0, 0);
    __builtin_amdgcn_s_setprio(0);
  }
  __syncthreads();   // all frag reads done before rp aliases the staging LDS

  // ---- epilogue (transposed C/D) ----
  // acc[ti][tj][r]: row = row0 + wrow + ti*16 + fr ; col = col0 + wcol + tj*16 + q*4 + r
#pragma unroll
  for (int ti = 0; ti < 4; ti++) {
    const int lrow = wrow + ti * 16 + fr;    // 0..127
    const int grow = row0 + lrow;
    float s[2][4];
#pragma unroll
    for (int tj = 0; tj < 2; tj++)
#pragma unroll
      for (int r = 0; r < 4; r++) {
        const int gcol = col0 + wcol + tj * 16 + q * 4 + r;
        s[tj][r] = (gcol < L) ? acc[ti][tj][r] * 10.0f : -1e30f;
      }
    float m = s[0][0];
#pragma unroll
    for (int tj = 0; tj < 2; tj++)
#pragma unroll
      for (int r = 0; r < 4; r++) m = fmaxf(m, s[tj][r]);
    m = fmaxf(m, __shfl_xor(m, 16, 64));
    m = fmaxf(m, __shfl_xor(m, 32, 64));

    float den = 0.f, msum = 0.f, cnt = 0.f, badf = 0.f;
#pragma unroll
    for (int tj = 0; tj < 2; tj++)
#pragma unroll
      for (int r = 0; r < 4; r++) {
        const int gcol = col0 + wcol + tj * 16 + q * 4 + r;
        if (gcol < L) {
          const float mk = (float)((mbits >> (ti * 8 + tj * 4 + r)) & 1u);
          if (gcol != grow) {
            den  += __expf(s[tj][r] - m);
            msum += mk * s[tj][r];
            cnt  += mk;
          }
          const float sane = (gcol == grow && grow != 0) ? 1.f : 0.f;
          badf = fmaxf(badf, (mk != sane) ? 1.f : 0.f);
        }
      }
    den  += __shfl_xor(den, 16, 64);  den  += __shfl_xor(den, 32, 64);
    msum += __shfl_xor(msum, 16, 64); msum += __shfl_xor(msum, 32, 64);
    cnt  += __shfl_xor(cnt, 16, 64);  cnt  += __shfl_xor(cnt, 32, 64);
    badf = fmaxf(badf, __shfl_xor(badf, 16, 64));
    badf = fmaxf(badf, __shfl_xor(badf, 32, 64));

    if (q == 0) {
      const int slot = wave & 3;
      rp_m[lrow * 4 + slot] = m;    rp_d[lrow * 4 + slot] = den;
      rp_s[lrow * 4 + slot] = msum; rp_c[lrow * 4 + slot] = cnt;
      rp_b[lrow * 4 + slot] = badf;
    }
  }
  __syncthreads();

  if (tid < 128) {
    float m = -1e30f;
#pragma unroll
    for (int s = 0; s < 4; s++) m = fmaxf(m, rp_m[tid * 4 + s]);
    float den = 0.f, msum = 0.f, cnt = 0.f, badf = 0.f;
#pragma unroll
    for (int s = 0; s < 4; s++) {
      den  += rp_d[tid * 4 + s] * __expf(rp_m[tid * 4 + s] - m);   // empty: 0*0
      msum += rp_s[tid * 4 + s];
      cnt  += rp_c[tid * 4 + s];
      badf  = fmaxf(badf, rp_b[tid * 4 + s]);
    }
    float* p = part + ((((size_t)b * 1024 + row0 + tid) * 8) + ct) * 5;
    p[0] = m; p[1] = den; p[2] = msum; p[3] = cnt; p[4] = badf;
  }
}

// ---------------- reduce: merge 8 column-tile slots per row ----------------
__global__ __launch_bounds__(256) void reduce_kernel(const float* __restrict__ part,
                                                     const int* __restrict__ icl,
                                                     float* __restrict__ blk_sum,
                                                     int* __restrict__ blk_bad) {
  const int blk = blockIdx.x;
  const int row = blk * 256 + threadIdx.x;   // 0..8191
  const int b = row >> 10;
  const int i = row & 1023;
  const int L = icl[b] + 1;
  float rv = 0.f;
  int bad = 0;
  if (i < L) {
    const float* p = part + (size_t)row * 40;
    const int ns = (L + 127) >> 7;           // valid slots
    float m = -1e30f;
    for (int s = 0; s < ns; s++) m = fmaxf(m, p[s * 5 + 0]);
    float den = 0.f, msum = 0.f, cnt = 0.f, badf = 0.f;
    for (int s = 0; s < ns; s++) {
      den  += p[s * 5 + 1] * __expf(p[s * 5 + 0] - m);
      msum += p[s * 5 + 2];
      cnt  += p[s * 5 + 3];
      badf  = fmaxf(badf, p[s * 5 + 4]);
    }
    const float A = msum - cnt * m;          // sum mask*(s - mx)
    const float mlpp = (A - cnt * __logf(den + 1e-6f)) / (cnt + 1e-6f);
    rv = -mlpp / (float)L;
    bad = badf > 0.f ? 1 : 0;
  }
  const int tid  = threadIdx.x;
  const int lane = tid & 63;
  const int wave = tid >> 6;
  for (int o = 32; o > 0; o >>= 1) rv += __shfl_down(rv, o, 64);
  const int wbad = (__ballot(bad) != 0ull) ? 1 : 0;
  __shared__ float sred[4];
  __shared__ int bred[4];
  if (lane == 0) { sred[wave] = rv; bred[wave] = wbad; }
  __syncthreads();
  if (tid == 0) {
    blk_sum[blk] = sred[0] + sred[1] + sred[2] + sred[3];
    blk_bad[blk] = bred[0] | bred[1] | bred[2] | bred[3];
  }
}

// ---------------- finalize (single wave, deterministic) ----------------
__global__ __launch_bounds__(64) void final_kernel(const float* __restrict__ blk_sum,
                                                   const int* __restrict__ blk_bad,
                                                   float* __restrict__ out) {
  const int tid = threadIdx.x;
  float v = (tid < 32) ? blk_sum[tid] : 0.f;
  for (int o = 32; o > 0; o >>= 1) v += __shfl_down(v, o, 64);
  if (tid == 0) {
    int vcount = 0;
    for (int bb = 0; bb < B_DIM; bb++) {
      const int any = blk_bad[bb * 4] | blk_bad[bb * 4 + 1] |
                      blk_bad[bb * 4 + 2] | blk_bad[bb * 4 + 3];
      vcount += any ? 1 : 0;
    }
    out[0] = v / fmaxf((float)vcount, 1.0f);
  }
}

extern "C" void kernel_launch(void* const* d_in, const int* in_sizes, int n_in,
                              void* d_out, int out_size, void* d_ws, size_t ws_size,
                              hipStream_t stream) {
  const float* feat = (const float*)d_in[0];
  const float* mask = (const float*)d_in[1];
  const int*   icl  = (const int*)d_in[2];
  float* out = (float*)d_out;

  char* ws = (char*)d_ws;
  __hip_bfloat16* Fb = (__hip_bfloat16*)ws;                 // 16 MiB
  float* part    = (float*)(ws + (16u << 20));              // 1.31 MiB
  float* blk_sum = (float*)(ws + (18u << 20));              // 128 B
  int*   blk_bad = (int*)(ws + (18u << 20) + 512);          // 128 B

  convert_kernel<<<dim3(8192), dim3(256), 0, stream>>>(feat, Fb);
  fused_kernel<<<dim3(512), dim3(512), 0, stream>>>(Fb, mask, icl, part);
  reduce_kernel<<<dim3(32), dim3(256), 0, stream>>>(part, icl, blk_sum, blk_bad);
  final_kernel<<<dim3(1), dim3(64), 0, stream>>>(blk_sum, blk_bad, out);
}

// Round 8
// 121.428 us; speedup vs baseline: 1.0785x; 1.0444x over previous
//
#include <hip/hip_runtime.h>
#include <hip/hip_bf16.h>
#include <stdint.h>

#define T_DIM 1024
#define B_DIM 8

typedef __attribute__((ext_vector_type(8))) short short8;
typedef __attribute__((ext_vector_type(4))) float f32x4;

__device__ inline void gll16(const void* g, void* l) {
  __builtin_amdgcn_global_load_lds((__attribute__((address_space(1))) void*)g,
                                   (__attribute__((address_space(3))) void*)l,
                                   16, 0, 0);
}

// ---------------- fp32 -> bf16 convert (row-gated) ----------------
// Rows >= L[b] are never validly consumed downstream (fused gates cols by
// gcol<L, reduce gates rows by i<L, fully-invalid tiles exit early), so skip
// them: ~25% less convert traffic. Each wave (64 thr x 4 elem = 256 elem)
// lies within one 1024-elem row -> the skip branch is wave-uniform.
__global__ __launch_bounds__(256) void convert_kernel(const float* __restrict__ F,
                                                      __hip_bfloat16* __restrict__ Fb,
                                                      const int* __restrict__ icl) {
  const int t = blockIdx.x * 256 + threadIdx.x;
  const int row = t >> 8;                 // 4 floats/thread, 256 threads/row
  const int L = icl[row >> 10] + 1;
  if ((row & 1023) >= L) return;
  const float4 v = ((const float4*)F)[t];
  union { __hip_bfloat16 h[4]; uint64_t u; } p;
  p.h[0] = __float2bfloat16(v.x);
  p.h[1] = __float2bfloat16(v.y);
  p.h[2] = __float2bfloat16(v.z);
  p.h[3] = __float2bfloat16(v.w);
  ((uint64_t*)Fb)[t] = p.u;
}

// ---------------- fused Gram + row-partial kernel ----------------
// EXACT round-3 structure (measured session best: 120.35 us, fused ~27 us).
// Ledger of failed variants (do not re-try): R2 counted-vmcnt restructure
// with hoisted frags (spill, +0), R4 reg-staging/convert-fusion (+20 us),
// R5 triangular 128^2 (occupancy 9 waves/CU, +5), R6 128x64 strips (+11),
// R7 mask-prologue-hoist (+6; epilogue mask latency is already hidden by
// the co-resident block's K-loop -- TLP solves it, hoisting hurts).
// Structure: 512 thr / 8 waves, 128^2 tile, BK=64 double-buffered gll16
// staging with counted vmcnt(4), XOR-swizzled LDS, swapped-operand MFMA
// (transposed C/D: lane fr = row -> row-reduction needs only 2 shuffles).
__global__ __launch_bounds__(512, 4) void fused_kernel(const __hip_bfloat16* __restrict__ Fb,
                                                       const float* __restrict__ M,
                                                       const int* __restrict__ icl,
                                                       float* __restrict__ part) {
  const int id = blockIdx.x;
  const int b  = id & 7;          // XCD = wgid % 8 -> all tiles of batch b on one XCD
  const int rt = (id >> 3) & 7;
  const int ct = id >> 6;
  const int L  = icl[b] + 1;
  if (rt * 128 >= L || ct * 128 >= L) return;   // tile fully invalid (uniform exit)

  __shared__ char smem[65536];
  __hip_bfloat16* As = (__hip_bfloat16*)smem;            // [2 buf][2 kk][128][32] = 32 KB
  __hip_bfloat16* Bs = (__hip_bfloat16*)(smem + 32768);  // 32 KB
  float* rp = (float*)smem;  // reused after K-loop: 5 arrays of 128x4 floats
  float* rp_m = rp;          // [row*4 + slot]
  float* rp_d = rp + 512;
  float* rp_s = rp + 1024;
  float* rp_c = rp + 1536;
  float* rp_b = rp + 2048;

  const __hip_bfloat16* F = Fb + ((size_t)b << 20);
  const int tid  = threadIdx.x;
  const int lane = tid & 63;
  const int wave = tid >> 6;            // 0..7
  const int wrow = (wave >> 2) * 64;    // 0 / 64
  const int wcol = (wave & 3) * 32;     // 0 / 32 / 64 / 96
  const int row0 = rt * 128;
  const int col0 = ct * 128;

  const int fr = lane & 15;             // fragment index within 16
  const int q  = lane >> 4;             // quarter-wave (k-granule)
  const int sl8 = (q ^ ((fr >> 1) & 3)) * 8;   // swizzled slot (elements)

  // staging: thread l -> LDS row l>>2, slot l&3; source granule = swizzle^-1
  const int srow = tid >> 2;                                  // 0..127
  const int sgk  = (((tid & 3) ^ ((tid >> 3) & 3)) * 8);      // source k offset

  const size_t arow = (size_t)(row0 + srow) * T_DIM + sgk;
  const size_t brow = (size_t)(col0 + srow) * T_DIM + sgk;

  auto stage = [&](int buf, int step) {
    const int kb = step << 6;     // BK = 64
#pragma unroll
    for (int p = 0; p < 2; p++)
      gll16(F + arow + kb + p * 32, As + buf * 8192 + p * 4096 + tid * 8);
#pragma unroll
    for (int p = 0; p < 2; p++)
      gll16(F + brow + kb + p * 32, Bs + buf * 8192 + p * 4096 + tid * 8);
  };

  // prologue: two tiles in flight (8 gll16)
  stage(0, 0);
  stage(1, 1);

  f32x4 acc[4][2];
#pragma unroll
  for (int i = 0; i < 4; i++)
#pragma unroll
    for (int j = 0; j < 2; j++) acc[i][j] = (f32x4){0.f, 0.f, 0.f, 0.f};

#pragma unroll
  for (int t = 0; t < 16; ++t) {
    const int cur = t & 1;
    // own tile-t loads landed; tile-(t+1) loads (4) stay in flight
    if (t < 15) { asm volatile("s_waitcnt vmcnt(4)" ::: "memory"); }
    else        { asm volatile("s_waitcnt vmcnt(0)" ::: "memory"); }
    __builtin_amdgcn_s_barrier();                 // (A) tile t visible everywhere
    __builtin_amdgcn_sched_barrier(0);

    short8 af[2][4], bfr[2][2];
    const __hip_bfloat16* Ab = As + cur * 8192;
    const __hip_bfloat16* Bb = Bs + cur * 8192;
#pragma unroll
    for (int kk = 0; kk < 2; kk++) {
#pragma unroll
      for (int tt = 0; tt < 4; tt++)
        af[kk][tt] = *(const short8*)(Ab + kk * 4096 + (wrow + tt * 16 + fr) * 32 + sl8);
#pragma unroll
      for (int j = 0; j < 2; j++)
        bfr[kk][j] = *(const short8*)(Bb + kk * 4096 + (wcol + j * 16 + fr) * 32 + sl8);
    }
    asm volatile("s_waitcnt lgkmcnt(0)" ::: "memory");
    __builtin_amdgcn_sched_barrier(0);
    __builtin_amdgcn_s_barrier();                 // (B) all reads done -> buf free
    __builtin_amdgcn_sched_barrier(0);

    if (t < 14) stage(cur, t + 2);                // refill freed buffer

    // SWAPPED operand order -> transposed C/D: lane fr = row, regs (q,r) = cols
    __builtin_amdgcn_s_setprio(1);
#pragma unroll
    for (int kk = 0; kk < 2; kk++)
#pragma unroll
      for (int ti = 0; ti < 4; ti++)
#pragma unroll
        for (int tj = 0; tj < 2; tj++)
          acc[ti][tj] = __builtin_amdgcn_mfma_f32_16x16x32_bf16(bfr[kk][tj], af[kk][ti], acc[ti][tj], 0, 0, 0);
    __builtin_amdgcn_s_setprio(0);
  }
  __syncthreads();   // all frag reads done before rp aliases the staging LDS

  // ---- epilogue (transposed C/D) ----
  // acc[ti][tj][r]: row = row0 + wrow + ti*16 + fr ; col = col0 + wcol + tj*16 + q*4 + r
  // mask loads here (NOT hoisted): co-resident block's K-loop hides their latency
  uint32_t mbits = 0;   // bit = ti*8 + tj*4 + r
  {
    const float* Mb = M + ((size_t)b << 20);
    union { float4 v; float f[4]; } mv[4][2];
#pragma unroll
    for (int ti = 0; ti < 4; ti++) {
      const int grow = row0 + wrow + ti * 16 + fr;
#pragma unroll
      for (int tj = 0; tj < 2; tj++)
        mv[ti][tj].v = *(const float4*)(Mb + ((size_t)grow << 10) + col0 + wcol + tj * 16 + q * 4);
    }
#pragma unroll
    for (int ti = 0; ti < 4; ti++)
#pragma unroll
      for (int tj = 0; tj < 2; tj++)
#pragma unroll
        for (int r = 0; r < 4; r++)
          mbits |= ((mv[ti][tj].f[r] != 0.f) ? 1u : 0u) << (ti * 8 + tj * 4 + r);
  }

#pragma unroll
  for (int ti = 0; ti < 4; ti++) {
    const int lrow = wrow + ti * 16 + fr;    // 0..127
    const int grow = row0 + lrow;
    float s[2][4];
#pragma unroll
    for (int tj = 0; tj < 2; tj++)
#pragma unroll
      for (int r = 0; r < 4; r++) {
        const int gcol = col0 + wcol + tj * 16 + q * 4 + r;
        s[tj][r] = (gcol < L) ? acc[ti][tj][r] * 10.0f : -1e30f;
      }
    float m = s[0][0];
#pragma unroll
    for (int tj = 0; tj < 2; tj++)
#pragma unroll
      for (int r = 0; r < 4; r++) m = fmaxf(m, s[tj][r]);
    m = fmaxf(m, __shfl_xor(m, 16, 64));
    m = fmaxf(m, __shfl_xor(m, 32, 64));

    float den = 0.f, msum = 0.f, cnt = 0.f, badf = 0.f;
#pragma unroll
    for (int tj = 0; tj < 2; tj++)
#pragma unroll
      for (int r = 0; r < 4; r++) {
        const int gcol = col0 + wcol + tj * 16 + q * 4 + r;
        if (gcol < L) {
          const float mk = (float)((mbits >> (ti * 8 + tj * 4 + r)) & 1u);
          if (gcol != grow) {
            den  += __expf(s[tj][r] - m);
            msum += mk * s[tj][r];
            cnt  += mk;
          }
          const float sane = (gcol == grow && grow != 0) ? 1.f : 0.f;
          badf = fmaxf(badf, (mk != sane) ? 1.f : 0.f);
        }
      }
    den  += __shfl_xor(den, 16, 64);  den  += __shfl_xor(den, 32, 64);
    msum += __shfl_xor(msum, 16, 64); msum += __shfl_xor(msum, 32, 64);
    cnt  += __shfl_xor(cnt, 16, 64);  cnt  += __shfl_xor(cnt, 32, 64);
    badf = fmaxf(badf, __shfl_xor(badf, 16, 64));
    badf = fmaxf(badf, __shfl_xor(badf, 32, 64));

    if (q == 0) {
      const int slot = wave & 3;
      rp_m[lrow * 4 + slot] = m;    rp_d[lrow * 4 + slot] = den;
      rp_s[lrow * 4 + slot] = msum; rp_c[lrow * 4 + slot] = cnt;
      rp_b[lrow * 4 + slot] = badf;
    }
  }
  __syncthreads();

  if (tid < 128) {
    float m = -1e30f;
#pragma unroll
    for (int s = 0; s < 4; s++) m = fmaxf(m, rp_m[tid * 4 + s]);
    float den = 0.f, msum = 0.f, cnt = 0.f, badf = 0.f;
#pragma unroll
    for (int s = 0; s < 4; s++) {
      den  += rp_d[tid * 4 + s] * __expf(rp_m[tid * 4 + s] - m);   // empty: 0*0
      msum += rp_s[tid * 4 + s];
      cnt  += rp_c[tid * 4 + s];
      badf  = fmaxf(badf, rp_b[tid * 4 + s]);
    }
    float* p = part + ((((size_t)b * 1024 + row0 + tid) * 8) + ct) * 5;
    p[0] = m; p[1] = den; p[2] = msum; p[3] = cnt; p[4] = badf;
  }
}

// ---------------- reduce: merge 8 column-tile slots per row ----------------
__global__ __launch_bounds__(256) void reduce_kernel(const float* __restrict__ part,
                                                     const int* __restrict__ icl,
                                                     float* __restrict__ blk_sum,
                                                     int* __restrict__ blk_bad) {
  const int blk = blockIdx.x;
  const int row = blk * 256 + threadIdx.x;   // 0..8191
  const int b = row >> 10;
  const int i = row & 1023;
  const int L = icl[b] + 1;
  float rv = 0.f;
  int bad = 0;
  if (i < L) {
    const float* p = part + (size_t)row * 40;
    const int ns = (L + 127) >> 7;           // valid slots
    float m = -1e30f;
    for (int s = 0; s < ns; s++) m = fmaxf(m, p[s * 5 + 0]);
    float den = 0.f, msum = 0.f, cnt = 0.f, badf = 0.f;
    for (int s = 0; s < ns; s++) {
      den  += p[s * 5 + 1] * __expf(p[s * 5 + 0] - m);
      msum += p[s * 5 + 2];
      cnt  += p[s * 5 + 3];
      badf  = fmaxf(badf, p[s * 5 + 4]);
    }
    const float A = msum - cnt * m;          // sum mask*(s - mx)
    const float mlpp = (A - cnt * __logf(den + 1e-6f)) / (cnt + 1e-6f);
    rv = -mlpp / (float)L;
    bad = badf > 0.f ? 1 : 0;
  }
  const int tid  = threadIdx.x;
  const int lane = tid & 63;
  const int wave = tid >> 6;
  for (int o = 32; o > 0; o >>= 1) rv += __shfl_down(rv, o, 64);
  const int wbad = (__ballot(bad) != 0ull) ? 1 : 0;
  __shared__ float sred[4];
  __shared__ int bred[4];
  if (lane == 0) { sred[wave] = rv; bred[wave] = wbad; }
  __syncthreads();
  if (tid == 0) {
    blk_sum[blk] = sred[0] + sred[1] + sred[2] + sred[3];
    blk_bad[blk] = bred[0] | bred[1] | bred[2] | bred[3];
  }
}

// ---------------- finalize (single wave, deterministic) ----------------
__global__ __launch_bounds__(64) void final_kernel(const float* __restrict__ blk_sum,
                                                   const int* __restrict__ blk_bad,
                                                   float* __restrict__ out) {
  const int tid = threadIdx.x;
  float v = (tid < 32) ? blk_sum[tid] : 0.f;
  for (int o = 32; o > 0; o >>= 1) v += __shfl_down(v, o, 64);
  if (tid == 0) {
    int vcount = 0;
    for (int bb = 0; bb < B_DIM; bb++) {
      const int any = blk_bad[bb * 4] | blk_bad[bb * 4 + 1] |
                      blk_bad[bb * 4 + 2] | blk_bad[bb * 4 + 3];
      vcount += any ? 1 : 0;
    }
    out[0] = v / fmaxf((float)vcount, 1.0f);
  }
}

extern "C" void kernel_launch(void* const* d_in, const int* in_sizes, int n_in,
                              void* d_out, int out_size, void* d_ws, size_t ws_size,
                              hipStream_t stream) {
  const float* feat = (const float*)d_in[0];
  const float* mask = (const float*)d_in[1];
  const int*   icl  = (const int*)d_in[2];
  float* out = (float*)d_out;

  char* ws = (char*)d_ws;
  __hip_bfloat16* Fb = (__hip_bfloat16*)ws;                 // 16 MiB
  float* part    = (float*)(ws + (16u << 20));              // 1.31 MiB
  float* blk_sum = (float*)(ws + (18u << 20));              // 128 B
  int*   blk_bad = (int*)(ws + (18u << 20) + 512);          // 128 B

  convert_kernel<<<dim3(8192), dim3(256), 0, stream>>>(feat, Fb, icl);
  fused_kernel<<<dim3(512), dim3(512), 0, stream>>>(Fb, mask, icl, part);
  reduce_kernel<<<dim3(32), dim3(256), 0, stream>>>(part, icl, blk_sum, blk_bad);
  final_kernel<<<dim3(1), dim3(64), 0, stream>>>(blk_sum, blk_bad, out);
}